// Round 1
// baseline (170.459 us; speedup 1.0000x reference)
//
#include <hip/hip_runtime.h>

// Capsule routing: B=256, J=2, N=6912, E=16, D=8, 2 routing iters. All fp32.
// R11: previous lane=b layout was LDS-issue-bound (576 ds_read_b128/thread/pass,
// 4 FMAs per read, LDS pipe is CU-shared => ~35-70us/pass vs 5.8us VALU floor).
// New layout: lane = (e:16, b_lo:4), each thread register-blocks 4 b's =>
// one W fragment (4 ds_read_b128) serves 64 FMAs; x comes via per-lane global
// loads (16-lane same-address broadcast, L1/L2). Waves own disjoint b's =>
// no intra-block reduction; partial layout & kred unchanged.
// Pass2 logit reduction over e done on the VALU pipe via DPP butterfly
// (xor1/xor2 quad_perm, xor7 row_half_mirror, xor15 row_mirror), reducing only
// delta = l1-l0 (4 values/thread/n); sigmoid uses v_rcp.
#define B_ 256
#define J_ 2
#define N_ 6912
#define E_ 16
#define D_ 8
#define NB 36     // n per block (all 4 waves iterate all 36)
#define CGX 192   // grid (CGX,4); 768 blocks = 256 CU x 3
#define BSTR (4*N_*D_)   // float stride between a thread's consecutive b's (4 rows)

// sum over the 16-lane row (e-lanes sharing b_lo), pure VALU/DPP:
__device__ __forceinline__ float dpp_row_add16(float v){
  v += __int_as_float(__builtin_amdgcn_update_dpp(0, __float_as_int(v), 0xB1,  0xF, 0xF, true)); // quad_perm [1,0,3,2]  : xor 1
  v += __int_as_float(__builtin_amdgcn_update_dpp(0, __float_as_int(v), 0x4E,  0xF, 0xF, true)); // quad_perm [2,3,0,1]  : xor 2
  v += __int_as_float(__builtin_amdgcn_update_dpp(0, __float_as_int(v), 0x141, 0xF, 0xF, true)); // row_half_mirror      : xor 7
  v += __int_as_float(__builtin_amdgcn_update_dpp(0, __float_as_int(v), 0x140, 0xF, 0xF, true)); // row_mirror           : xor 15
  return v;
}

// ---------------- main path ----------------

__global__ __launch_bounds__(256, 3) void kpass1(const float* __restrict__ x,
                                                 const float* __restrict__ W,
                                                 float* __restrict__ partial)
{
  __shared__ float smem[9216];   // 36KB: W[j][36n][16e][8d] linear
  const int tid  = threadIdx.x;
  const int lane = tid & 63;
  const int wv   = __builtin_amdgcn_readfirstlane(tid >> 6);
  const int e    = lane & 15;
  const int blo  = lane >> 4;
  const int nb0  = blockIdx.x * NB;

  // stage W slice -> smem (coalesced, conflict-free)
  float4 wbuf[9];
  #pragma unroll
  for (int k=0;k<9;++k){
    const int idx = k*256 + tid;            // float4 idx 0..2303
    const int j   = (idx >= 1152) ? 1 : 0;
    const int r4  = idx - j*1152;
    wbuf[k] = *(const float4*)(W + ((size_t)j*N_ + nb0)*(E_*D_) + (size_t)r4*4);
  }
  #pragma unroll
  for (int k=0;k<9;++k)
    *(float4*)(smem + (size_t)(k*256 + tid)*4) = wbuf[k];

  const int b0 = blockIdx.y*64 + wv*16 + blo;     // thread's first b (others: +4k)
  const float* xp = x + ((size_t)b0*N_ + nb0)*D_;

  float4 xa[4], xb[4];                            // next-n prefetch regs
  #pragma unroll
  for (int k=0;k<4;++k){
    xa[k] = *(const float4*)(xp + (size_t)k*BSTR);
    xb[k] = *(const float4*)(xp + (size_t)k*BSTR + 4);
  }
  __syncthreads();

  float acc0[4] = {0,0,0,0}, acc1[4] = {0,0,0,0};
  #pragma unroll 1
  for (int ni=0; ni<NB; ++ni){
    float4 ca[4], cb[4];
    #pragma unroll
    for (int k=0;k<4;++k){ ca[k]=xa[k]; cb[k]=xb[k]; }
    if (ni+1 < NB){
      #pragma unroll
      for (int k=0;k<4;++k){
        xa[k] = *(const float4*)(xp + (size_t)k*BSTR + (ni+1)*8);
        xb[k] = *(const float4*)(xp + (size_t)k*BSTR + (ni+1)*8 + 4);
      }
    }
    const float* wp0 = smem + ni*(E_*D_) + e*8;   // j=0; j=1 at +NB*128
    const float4 wa0 = *(const float4*)(wp0);
    const float4 wb0 = *(const float4*)(wp0 + 4);
    const float4 wa1 = *(const float4*)(wp0 + NB*(E_*D_));
    const float4 wb1 = *(const float4*)(wp0 + NB*(E_*D_) + 4);
    #pragma unroll
    for (int k=0;k<4;++k){
      float a0 = acc0[k], a1 = acc1[k];
      a0 = fmaf(wa0.x, ca[k].x, a0); a0 = fmaf(wa0.y, ca[k].y, a0);
      a0 = fmaf(wa0.z, ca[k].z, a0); a0 = fmaf(wa0.w, ca[k].w, a0);
      a0 = fmaf(wb0.x, cb[k].x, a0); a0 = fmaf(wb0.y, cb[k].y, a0);
      a0 = fmaf(wb0.z, cb[k].z, a0); a0 = fmaf(wb0.w, cb[k].w, a0);
      a1 = fmaf(wa1.x, ca[k].x, a1); a1 = fmaf(wa1.y, ca[k].y, a1);
      a1 = fmaf(wa1.z, ca[k].z, a1); a1 = fmaf(wa1.w, ca[k].w, a1);
      a1 = fmaf(wb1.x, cb[k].x, a1); a1 = fmaf(wb1.y, cb[k].y, a1);
      a1 = fmaf(wb1.z, cb[k].z, a1); a1 = fmaf(wb1.w, cb[k].w, a1);
      acc0[k] = a0; acc1[k] = a1;
    }
  }

  // waves own disjoint b's: store partials directly (16-lane contiguous 64B)
  float* dst = partial + (size_t)(blockIdx.x*4 + blockIdx.y)*2048
             + (wv*16 + blo)*32 + e;
  #pragma unroll
  for (int k=0;k<4;++k){
    dst[k*128]      = acc0[k];
    dst[k*128 + 16] = acc1[k];
  }
}

__global__ __launch_bounds__(256, 3) void kpass2(const float* __restrict__ x,
                                                 const float* __restrict__ W,
                                                 const float* __restrict__ v1,
                                                 float* __restrict__ partial)
{
  __shared__ float smem[9216];
  const int tid  = threadIdx.x;
  const int lane = tid & 63;
  const int wv   = __builtin_amdgcn_readfirstlane(tid >> 6);
  const int e    = lane & 15;
  const int blo  = lane >> 4;
  const int nb0  = blockIdx.x * NB;

  float4 wbuf[9];
  #pragma unroll
  for (int k=0;k<9;++k){
    const int idx = k*256 + tid;
    const int j   = (idx >= 1152) ? 1 : 0;
    const int r4  = idx - j*1152;
    wbuf[k] = *(const float4*)(W + ((size_t)j*N_ + nb0)*(E_*D_) + (size_t)r4*4);
  }
  #pragma unroll
  for (int k=0;k<9;++k)
    *(float4*)(smem + (size_t)(k*256 + tid)*4) = wbuf[k];

  const int b0 = blockIdx.y*64 + wv*16 + blo;
  const float* xp = x + ((size_t)b0*N_ + nb0)*D_;

  float4 xa[4], xb[4];
  #pragma unroll
  for (int k=0;k<4;++k){
    xa[k] = *(const float4*)(xp + (size_t)k*BSTR);
    xb[k] = *(const float4*)(xp + (size_t)k*BSTR + 4);
  }
  float vj0[4], vj1[4];
  #pragma unroll
  for (int k=0;k<4;++k){
    vj0[k] = v1[(size_t)(b0 + 4*k)*32 + e];
    vj1[k] = v1[(size_t)(b0 + 4*k)*32 + 16 + e];
  }
  __syncthreads();

  float acc0[4] = {0,0,0,0}, acc1[4] = {0,0,0,0};
  #pragma unroll 1
  for (int ni=0; ni<NB; ++ni){
    float4 ca[4], cb[4];
    #pragma unroll
    for (int k=0;k<4;++k){ ca[k]=xa[k]; cb[k]=xb[k]; }
    if (ni+1 < NB){
      #pragma unroll
      for (int k=0;k<4;++k){
        xa[k] = *(const float4*)(xp + (size_t)k*BSTR + (ni+1)*8);
        xb[k] = *(const float4*)(xp + (size_t)k*BSTR + (ni+1)*8 + 4);
      }
    }
    const float* wp0 = smem + ni*(E_*D_) + e*8;
    const float4 wa0 = *(const float4*)(wp0);
    const float4 wb0 = *(const float4*)(wp0 + 4);
    const float4 wa1 = *(const float4*)(wp0 + NB*(E_*D_));
    const float4 wb1 = *(const float4*)(wp0 + NB*(E_*D_) + 4);

    float u0[4], u1[4];
    #pragma unroll
    for (int k=0;k<4;++k){
      float a0, a1;
      a0 = wa0.x*ca[k].x;        a0 = fmaf(wa0.y, ca[k].y, a0);
      a0 = fmaf(wa0.z, ca[k].z, a0); a0 = fmaf(wa0.w, ca[k].w, a0);
      a0 = fmaf(wb0.x, cb[k].x, a0); a0 = fmaf(wb0.y, cb[k].y, a0);
      a0 = fmaf(wb0.z, cb[k].z, a0); a0 = fmaf(wb0.w, cb[k].w, a0);
      a1 = wa1.x*ca[k].x;        a1 = fmaf(wa1.y, ca[k].y, a1);
      a1 = fmaf(wa1.z, ca[k].z, a1); a1 = fmaf(wa1.w, ca[k].w, a1);
      a1 = fmaf(wb1.x, cb[k].x, a1); a1 = fmaf(wb1.y, cb[k].y, a1);
      a1 = fmaf(wb1.z, cb[k].z, a1); a1 = fmaf(wb1.w, cb[k].w, a1);
      u0[k] = a0; u1[k] = a1;
    }
    #pragma unroll
    for (int k=0;k<4;++k){
      // delta = l1 - l0, summed over the 16 e-lanes on the VALU pipe
      const float d  = dpp_row_add16(fmaf(vj1[k], u1[k], -(vj0[k]*u0[k])));
      const float c0 = __builtin_amdgcn_rcpf(1.f + __expf(d));   // softmax over 2 caps
      acc0[k] = fmaf(c0,       u0[k], acc0[k]);
      acc1[k] = fmaf(1.f - c0, u1[k], acc1[k]);
    }
  }

  float* dst = partial + (size_t)(blockIdx.x*4 + blockIdx.y)*2048
             + (wv*16 + blo)*32 + e;
  #pragma unroll
  for (int k=0;k<4;++k){
    dst[k*128]      = acc0[k];
    dst[k*128 + 16] = acc1[k];
  }
}

// Fused reduce (sum 192 chunk-partials) + squash (16-lane shfl butterfly).
template<bool HALF>
__global__ __launch_bounds__(256) void kred(const float* __restrict__ partial,
                                            float* __restrict__ dst)
{
  const int t = blockIdx.x*256 + threadIdx.x;     // grid 32 -> 8192
  const int btile = t >> 11, q = t & 2047;
  const float* p = partial + (size_t)btile*2048 + q;
  float s = 0.f;
  #pragma unroll 8
  for (int cx=0; cx<CGX; ++cx) s += p[(size_t)cx*8192];
  if (HALF) s *= 0.5f;
  float n2 = s*s;
  #pragma unroll
  for (int m=1; m<16; m<<=1) n2 += __shfl_xor(n2, m);
  const float f = (n2/(1.f+n2)) * rsqrtf(n2 + 1e-9f);
  dst[t] = s * f;
}

// ---------------- fallback: R5 monolithic (no ws) ----------------
#define NT 512
__global__ __launch_bounds__(NT) void kmono(const float* __restrict__ x,
                                            const float* __restrict__ W,
                                            float* __restrict__ out)
{
  const int b    = blockIdx.x;
  const int tid  = threadIdx.x;
  const int wv   = tid >> 6;
  const int lane = tid & 63;
  __shared__ float wred[8*33];
  __shared__ float vsh[32];

  float acc[32];
  #pragma unroll
  for (int i=0;i<32;++i) acc[i]=0.f;
  for (int n = tid; n < N_; n += NT){
    const float4 xa = *(const float4*)(x + ((size_t)b*N_ + n)*D_);
    const float4 xb = *(const float4*)(x + ((size_t)b*N_ + n)*D_ + 4);
    #pragma unroll
    for (int j=0;j<J_;++j){
      const float* wp = W + ((size_t)j*N_ + n)*(E_*D_);
      #pragma unroll
      for (int e=0;e<E_;++e){
        const float4 wa = *(const float4*)(wp + e*8);
        const float4 wb = *(const float4*)(wp + e*8 + 4);
        float a = acc[j*16+e];
        a = fmaf(wa.x,xa.x,a); a = fmaf(wa.y,xa.y,a); a = fmaf(wa.z,xa.z,a); a = fmaf(wa.w,xa.w,a);
        a = fmaf(wb.x,xb.x,a); a = fmaf(wb.y,xb.y,a); a = fmaf(wb.z,xb.z,a); a = fmaf(wb.w,xb.w,a);
        acc[j*16+e] = a;
      }
    }
  }
  #pragma unroll
  for (int i=0;i<32;++i){
    float v = acc[i];
    #pragma unroll
    for (int off=32; off; off>>=1) v += __shfl_xor(v, off);
    acc[i] = v;
  }
  if (lane == 0){
    #pragma unroll
    for (int i=0;i<32;++i) wred[wv*33 + i] = acc[i];
  }
  __syncthreads();
  if (tid < 32){
    float s = 0.f;
    #pragma unroll
    for (int w=0;w<8;++w) s += wred[w*33 + tid];
    wred[tid] = 0.5f * s;
  }
  __syncthreads();
  if (tid < 32){
    const int j = tid >> 4; float n2 = 0.f;
    #pragma unroll
    for (int e=0;e<16;++e){ const float sv = wred[j*16+e]; n2 = fmaf(sv,sv,n2); }
    vsh[tid] = wred[tid] * (n2/(1.f+n2)) * rsqrtf(n2 + 1e-9f);
  }
  __syncthreads();
  float vv[32];
  #pragma unroll
  for (int i=0;i<32;++i) vv[i] = vsh[i];

  #pragma unroll
  for (int i=0;i<32;++i) acc[i]=0.f;
  for (int n = tid; n < N_; n += NT){
    const float4 xa = *(const float4*)(x + ((size_t)b*N_ + n)*D_);
    const float4 xb = *(const float4*)(x + ((size_t)b*N_ + n)*D_ + 4);
    float u[32];
    #pragma unroll
    for (int j=0;j<J_;++j){
      const float* wp = W + ((size_t)j*N_ + n)*(E_*D_);
      #pragma unroll
      for (int e=0;e<E_;++e){
        const float4 wa = *(const float4*)(wp + e*8);
        const float4 wb = *(const float4*)(wp + e*8 + 4);
        float a;
        a = wa.x*xa.x; a = fmaf(wa.y,xa.y,a); a = fmaf(wa.z,xa.z,a); a = fmaf(wa.w,xa.w,a);
        a = fmaf(wb.x,xb.x,a); a = fmaf(wb.y,xb.y,a); a = fmaf(wb.z,xb.z,a); a = fmaf(wb.w,xb.w,a);
        u[j*16+e] = a;
      }
    }
    float l0=0.f, l1=0.f;
    #pragma unroll
    for (int e=0;e<16;++e){ l0 = fmaf(vv[e],u[e],l0); l1 = fmaf(vv[16+e],u[16+e],l1); }
    const float c0 = 1.f/(1.f + __expf(l1 - l0));
    const float c1 = 1.f - c0;
    #pragma unroll
    for (int e=0;e<16;++e){ acc[e] = fmaf(c0,u[e],acc[e]); acc[16+e] = fmaf(c1,u[16+e],acc[16+e]); }
  }
  #pragma unroll
  for (int i=0;i<32;++i){
    float v = acc[i];
    #pragma unroll
    for (int off=32; off; off>>=1) v += __shfl_xor(v, off);
    acc[i] = v;
  }
  __syncthreads();
  if (lane == 0){
    #pragma unroll
    for (int i=0;i<32;++i) wred[wv*33 + i] = acc[i];
  }
  __syncthreads();
  if (tid < 32){
    float s = 0.f;
    #pragma unroll
    for (int w=0;w<8;++w) s += wred[w*33 + tid];
    wred[tid] = s;
  }
  __syncthreads();
  if (tid < 32){
    const int j = tid >> 4; float n2 = 0.f;
    #pragma unroll
    for (int e=0;e<16;++e){ const float sv = wred[j*16+e]; n2 = fmaf(sv,sv,n2); }
    out[(size_t)b*32 + tid] = wred[tid] * (n2/(1.f+n2)) * rsqrtf(n2 + 1e-9f);
  }
}

extern "C" void kernel_launch(void* const* d_in, const int* in_sizes, int n_in,
                              void* d_out, int out_size, void* d_ws, size_t ws_size,
                              hipStream_t stream)
{
  const float* x = (const float*)d_in[0];   // [256,6912,8]
  const float* W = (const float*)d_in[1];   // [2,6912,16,8]
  if (n_in >= 2 && in_sizes[0] < in_sizes[1]){
    x = (const float*)d_in[1]; W = (const float*)d_in[0];
  }
  float* out = (float*)d_out;               // fp32 [256,2,16]

  const size_t need_main = (size_t)(8192 + 768*2048) * sizeof(float);  // ~6.1 MB

  if (ws_size >= need_main){
    float* wsf     = (float*)d_ws;
    float* v1      = wsf;           // 8192 floats
    float* partial = wsf + 8192;    // 768*2048 floats
    kpass1<<<dim3(CGX,4), 256, 0, stream>>>(x, W, partial);
    kred<true ><<<32, 256, 0, stream>>>(partial, v1);
    kpass2<<<dim3(CGX,4), 256, 0, stream>>>(x, W, v1, partial);
    kred<false><<<32, 256, 0, stream>>>(partial, out);
  } else {
    kmono<<<B_, NT, 0, stream>>>(x, W, out);
  }
}